// Round 1
// baseline (438.298 us; speedup 1.0000x reference)
//
#include <hip/hip_runtime.h>
#include <math.h>

// downprompt: fused elementwise + 7-way cosine-sim + softmax.
// One wave (64 lanes) per row; lane l owns columns 4l..4l+3 (float4 loads).
// Row-independent coef[d] and ave fragments live in registers, amortized
// over ~24 rows/wave via grid-stride loop.

__device__ __forceinline__ float elu1(float x) {
    return x > 0.0f ? x : __expf(x) - 1.0f;
}

__device__ __forceinline__ float wave_sum(float v) {
#pragma unroll
    for (int off = 32; off > 0; off >>= 1)
        v += __shfl_xor(v, off, 64);
    return v;
}

__global__ __launch_bounds__(256) void downprompt_kernel(
    const float* __restrict__ seq,
    const float* __restrict__ seq1,
    const float* __restrict__ prompt,
    const float* __restrict__ w_np,
    const float* __restrict__ w_ds,
    const float* __restrict__ w_df,
    const float* __restrict__ ave,
    float* __restrict__ out,
    int N)
{
    const int lane = threadIdx.x & 63;
    const int wavesPerBlock = blockDim.x >> 6;
    const int gwave = blockIdx.x * wavesPerBlock + (threadIdx.x >> 6);
    const int nwave = gridDim.x * wavesPerBlock;
    const int d0 = lane << 2;   // column base for this lane

    // ---- per-wave setup (row-independent) ----
    const float a  = w_df[0];
    const float b  = w_df[1];
    const float w0 = w_np[0], w1 = w_np[1], w2 = w_np[2];

    const float4 p0 = *(const float4*)(prompt +   0 + d0);
    const float4 p1 = *(const float4*)(prompt + 256 + d0);
    const float4 p2 = *(const float4*)(prompt + 512 + d0);
    const float4 wd = *(const float4*)(w_ds + d0);

    // coef[d] = a*(1+elu((w_np@prompt)[d])) + b*w_ds[d]
    float coef[4];
    coef[0] = a * (1.0f + elu1(w0*p0.x + w1*p1.x + w2*p2.x)) + b * wd.x;
    coef[1] = a * (1.0f + elu1(w0*p0.y + w1*p1.y + w2*p2.y)) + b * wd.y;
    coef[2] = a * (1.0f + elu1(w0*p0.z + w1*p1.z + w2*p2.z)) + b * wd.z;
    coef[3] = a * (1.0f + elu1(w0*p0.w + w1*p1.w + w2*p2.w)) + b * wd.w;

    // ave fragments (7 x 4 floats per lane) + prototype norms
    float av[7][4];
    float na[7];
#pragma unroll
    for (int c = 0; c < 7; ++c) {
        const float4 v = *(const float4*)(ave + c * 256 + d0);
        av[c][0] = v.x; av[c][1] = v.y; av[c][2] = v.z; av[c][3] = v.w;
        const float p = v.x*v.x + v.y*v.y + v.z*v.z + v.w*v.w;
        na[c] = sqrtf(wave_sum(p));
    }

    // ---- grid-stride over rows, one wave per row ----
    for (int row = gwave; row < N; row += nwave) {
        const float4 s = *(const float4*)(seq  + (size_t)row * 256 + d0);
        const float4 t = *(const float4*)(seq1 + (size_t)row * 256 + d0);

        float r[4];
        r[0] = elu1(coef[0] * s.x) + 0.1f * t.x;
        r[1] = elu1(coef[1] * s.y) + 0.1f * t.y;
        r[2] = elu1(coef[2] * s.z) + 0.1f * t.z;
        r[3] = elu1(coef[3] * s.w) + 0.1f * t.w;

        float acc[8];
#pragma unroll
        for (int c = 0; c < 7; ++c)
            acc[c] = r[0]*av[c][0] + r[1]*av[c][1] + r[2]*av[c][2] + r[3]*av[c][3];
        acc[7] = r[0]*r[0] + r[1]*r[1] + r[2]*r[2] + r[3]*r[3];

        // 8 interleaved butterfly reductions across the 64-lane wave
#pragma unroll
        for (int off = 32; off > 0; off >>= 1) {
#pragma unroll
            for (int k = 0; k < 8; ++k)
                acc[k] += __shfl_xor(acc[k], off, 64);
        }

        // every lane now holds all 8 sums; compute softmax redundantly
        const float nr = sqrtf(acc[7]);
        float sims[7];
        float m = -INFINITY;
#pragma unroll
        for (int c = 0; c < 7; ++c) {
            const float den = fmaxf(nr * na[c], 1e-8f);
            sims[c] = acc[c] * __builtin_amdgcn_rcpf(den);
            m = fmaxf(m, sims[c]);
        }
        float sum = 0.0f, mye = 0.0f;
#pragma unroll
        for (int c = 0; c < 7; ++c) {
            const float e = __expf(sims[c] - m);
            sum += e;
            if (lane == c) mye = e;
        }
        if (lane < 7)
            out[(size_t)row * 7 + lane] = mye * __builtin_amdgcn_rcpf(sum);
    }
}

extern "C" void kernel_launch(void* const* d_in, const int* in_sizes, int n_in,
                              void* d_out, int out_size, void* d_ws, size_t ws_size,
                              hipStream_t stream) {
    const float* seq    = (const float*)d_in[0];
    const float* seq1   = (const float*)d_in[1];
    const float* prompt = (const float*)d_in[2];
    const float* w_np   = (const float*)d_in[3];
    const float* w_ds   = (const float*)d_in[4];
    const float* w_df   = (const float*)d_in[5];
    const float* ave    = (const float*)d_in[6];
    float* out = (float*)d_out;

    const int N = in_sizes[0] / 256;   // 200000

    // 2048 blocks x 256 threads = 8192 waves; grid-stride -> ~24 rows/wave,
    // amortizing the per-wave setup (coef, ave fragments, prototype norms).
    downprompt_kernel<<<2048, 256, 0, stream>>>(seq, seq1, prompt, w_np, w_ds,
                                                w_df, ave, out, N);
}